// Round 1
// baseline (235.097 us; speedup 1.0000x reference)
//
#include <hip/hip_runtime.h>
#include <hip/hip_bf16.h>

// Problem constants (B=8, T=2048, C=1024, H=64)
#define TB 2048
#define NB 8
#define CEMB 1024
#define HD 64
#define BT (NB*TB)           // 16384 flattened rows
#define SCALE 0.03125f       // 1/sqrt(1024) — reference scales by n_embd, not head_size

typedef __attribute__((ext_vector_type(8))) short bf16x8;
typedef __attribute__((ext_vector_type(4))) float f32x4;

__device__ inline short f2bf(float f) {
    union { float f; unsigned u; } v; v.f = f;
    unsigned r = v.u + 0x7fffu + ((v.u >> 16) & 1u);   // RNE
    return (short)(r >> 16);
}

// ---------------- Kernel 1: W fp32 -> bf16 concat [Wk;Wq;Wv] = [192][1024] ----------------
__global__ __launch_bounds__(256) void wconvert(const float* __restrict__ Wk,
                                                const float* __restrict__ Wq,
                                                const float* __restrict__ Wv,
                                                short* __restrict__ Wcat) {
    int e = (blockIdx.x * 256 + threadIdx.x) * 4;   // 192 blocks -> 196608 elems
    int row = e >> 10;
    int col = e & 1023;
    const float* src = (row < 64) ? (Wk + row * 1024)
                     : (row < 128) ? (Wq + (row - 64) * 1024)
                                   : (Wv + (row - 128) * 1024);
    float4 v = *reinterpret_cast<const float4*>(src + col);
    short4 o; o.x = f2bf(v.x); o.y = f2bf(v.y); o.z = f2bf(v.z); o.w = f2bf(v.w);
    *reinterpret_cast<short4*>(Wcat + e) = o;
}

// ---------------- Kernel 2: QKV projection (bf16 MFMA) ----------------
// qkv[m][n] = sum_c x[m][c] * Wcat[n][c];  n-tiles 0..3 -> K, 4..7 -> Q, 8..11 -> V
#define WPAD 72   // 64 cols + 8 pad (bf16) -> row stride 144 B, 2-way bank alias only
__global__ __launch_bounds__(256) void qkv_proj(const float* __restrict__ x,
                                                const short* __restrict__ Wcat,
                                                short* __restrict__ Qb,
                                                short* __restrict__ Kb,
                                                short* __restrict__ Vb) {
    __shared__ short Wsh[192 * WPAD];
    int tid  = threadIdx.x;
    int wave = tid >> 6;
    int lane = tid & 63;
    int l15  = lane & 15;
    int quad = lane >> 4;
    int m0   = blockIdx.x * 64;
    int mrow = m0 + wave * 16 + l15;       // A-frag row (m = lane&15)

    f32x4 acc[12];
#pragma unroll
    for (int i = 0; i < 12; ++i) acc[i] = f32x4{0.f, 0.f, 0.f, 0.f};

    for (int kc = 0; kc < 16; ++kc) {      // K chunks of 64
        __syncthreads();
        // stage Wcat[:, kc*64 .. +63] into LDS (192 rows x 8 x 16B chunks)
#pragma unroll
        for (int j = 0; j < 6; ++j) {
            int c   = tid + 256 * j;       // 0..1535
            int row = c >> 3;
            int off = (c & 7) * 8;
            *reinterpret_cast<int4*>(&Wsh[row * WPAD + off]) =
                *reinterpret_cast<const int4*>(Wcat + row * 1024 + kc * 64 + off);
        }
        __syncthreads();
#pragma unroll
        for (int ks = 0; ks < 2; ++ks) {   // two K=32 MFMA steps
            const float4* xs = reinterpret_cast<const float4*>(
                x + (size_t)mrow * CEMB + kc * 64 + ks * 32 + quad * 8);
            float4 x0 = xs[0], x1 = xs[1];
            bf16x8 af;
            af[0] = f2bf(x0.x); af[1] = f2bf(x0.y); af[2] = f2bf(x0.z); af[3] = f2bf(x0.w);
            af[4] = f2bf(x1.x); af[5] = f2bf(x1.y); af[6] = f2bf(x1.z); af[7] = f2bf(x1.w);
            int kb = ks * 32 + quad * 8;
#pragma unroll
            for (int nt = 0; nt < 12; ++nt) {
                bf16x8 bf = *reinterpret_cast<const bf16x8*>(&Wsh[(nt * 16 + l15) * WPAD + kb]);
                acc[nt] = __builtin_amdgcn_mfma_f32_16x16x32_bf16(af, bf, acc[nt], 0, 0, 0);
            }
        }
    }
    // epilogue: C layout col=lane&15, row=quad*4+reg
#pragma unroll
    for (int nt = 0; nt < 12; ++nt) {
        short* dst = (nt < 4) ? Kb : (nt < 8) ? Qb : Vb;
        int h = (nt & 3) * 16 + l15;
#pragma unroll
        for (int r = 0; r < 4; ++r) {
            int m = m0 + wave * 16 + quad * 4 + r;
            dst[m * HD + h] = f2bf(acc[nt][r]);
        }
    }
}

// ---------------- Kernel 3: causal flash attention ----------------
#define KPAD 72   // K tile: 32 rows x (64+8) bf16
#define VPAD 40   // V^T / P tiles: rows x (32+8) bf16
__global__ __launch_bounds__(256) void flash(const short* __restrict__ Qb,
                                             const short* __restrict__ Kb,
                                             const short* __restrict__ Vb,
                                             float* __restrict__ out) {
    __shared__ short Ksh[32 * KPAD];
    __shared__ short Vsh[64 * VPAD];          // V transposed: [h][s]
    __shared__ short Psh[4][16 * VPAD];       // per-wave P relayout buffer
    int tid  = threadIdx.x;
    int wave = tid >> 6;
    int lane = tid & 63;
    int l15  = lane & 15;
    int quad = lane >> 4;
    int b  = blockIdx.x >> 5;
    int qt = blockIdx.x & 31;
    int t0 = qt * 64;
    int tq = t0 + wave * 16 + l15;            // this lane's query row for A-frags

    // Q fragments (held for whole kernel): A[m=lane&15][k=quad*8+j]
    const short* qrow = Qb + (b * TB + tq) * HD;
    bf16x8 qf0 = *reinterpret_cast<const bf16x8*>(qrow + quad * 8);
    bf16x8 qf1 = *reinterpret_cast<const bf16x8*>(qrow + 32 + quad * 8);

    f32x4 accO[4];
#pragma unroll
    for (int i = 0; i < 4; ++i) accO[i] = f32x4{0.f, 0.f, 0.f, 0.f};
    float mrow[4], lrow[4];
#pragma unroll
    for (int r = 0; r < 4; ++r) { mrow[r] = -1e30f; lrow[r] = 0.f; }

    int ntiles = (t0 + 64) / 32;              // uniform per block -> barriers legal
    for (int st = 0; st < ntiles; ++st) {
        int s0 = st * 32;
        __syncthreads();
        {   // stage K (row-major) and V (transposed) tiles
            int row = tid >> 3;               // 0..31
            int off = (tid & 7) * 8;          // 0..56
            const short* ksrc = Kb + (b * TB + s0 + row) * HD + off;
            *reinterpret_cast<int4*>(&Ksh[row * KPAD + off]) =
                *reinterpret_cast<const int4*>(ksrc);
            const short* vsrc = Vb + (b * TB + s0 + row) * HD + off;
            short v8[8];
            *reinterpret_cast<int4*>(v8) = *reinterpret_cast<const int4*>(vsrc);
#pragma unroll
            for (int j = 0; j < 8; ++j) Vsh[(off + j) * VPAD + row] = v8[j];
        }
        __syncthreads();

        // S = Q K^T : two 16(q) x 16(s) C-tiles
        f32x4 s0v = f32x4{0.f, 0.f, 0.f, 0.f};
        f32x4 s1v = f32x4{0.f, 0.f, 0.f, 0.f};
        {
            bf16x8 k00 = *reinterpret_cast<const bf16x8*>(&Ksh[l15 * KPAD + quad * 8]);
            bf16x8 k01 = *reinterpret_cast<const bf16x8*>(&Ksh[l15 * KPAD + 32 + quad * 8]);
            bf16x8 k10 = *reinterpret_cast<const bf16x8*>(&Ksh[(16 + l15) * KPAD + quad * 8]);
            bf16x8 k11 = *reinterpret_cast<const bf16x8*>(&Ksh[(16 + l15) * KPAD + 32 + quad * 8]);
            s0v = __builtin_amdgcn_mfma_f32_16x16x32_bf16(qf0, k00, s0v, 0, 0, 0);
            s0v = __builtin_amdgcn_mfma_f32_16x16x32_bf16(qf1, k01, s0v, 0, 0, 0);
            s1v = __builtin_amdgcn_mfma_f32_16x16x32_bf16(qf0, k10, s1v, 0, 0, 0);
            s1v = __builtin_amdgcn_mfma_f32_16x16x32_bf16(qf1, k11, s1v, 0, 0, 0);
        }

        // online softmax; C layout: col(s)=lane&15, row(t)=quad*4+r
        int sgl = s0 + l15;
#pragma unroll
        for (int r = 0; r < 4; ++r) {
            int tg = t0 + wave * 16 + quad * 4 + r;
            float v0 = (sgl      <= tg) ? s0v[r] * SCALE : -1e30f;
            float v1 = (sgl + 16 <= tg) ? s1v[r] * SCALE : -1e30f;
            float mx = fmaxf(v0, v1);
            mx = fmaxf(mx, __shfl_xor(mx, 1));
            mx = fmaxf(mx, __shfl_xor(mx, 2));
            mx = fmaxf(mx, __shfl_xor(mx, 4));
            mx = fmaxf(mx, __shfl_xor(mx, 8));
            float mn = fmaxf(mrow[r], mx);
            float e0 = __expf(v0 - mn);
            float e1 = __expf(v1 - mn);
            float rs = e0 + e1;
            rs += __shfl_xor(rs, 1);
            rs += __shfl_xor(rs, 2);
            rs += __shfl_xor(rs, 4);
            rs += __shfl_xor(rs, 8);
            float alpha = __expf(mrow[r] - mn);
            lrow[r] = lrow[r] * alpha + rs;
            mrow[r] = mn;
#pragma unroll
            for (int ht = 0; ht < 4; ++ht) accO[ht][r] *= alpha;
            Psh[wave][(quad * 4 + r) * VPAD + l15]      = f2bf(e0);
            Psh[wave][(quad * 4 + r) * VPAD + 16 + l15] = f2bf(e1);
        }
        __syncthreads();

        // O += P V : P as A-frag (k=s over 32), V^T as B-frag (n=h, k=s)
        bf16x8 pf = *reinterpret_cast<const bf16x8*>(&Psh[wave][l15 * VPAD + quad * 8]);
#pragma unroll
        for (int ht = 0; ht < 4; ++ht) {
            bf16x8 vf = *reinterpret_cast<const bf16x8*>(&Vsh[(ht * 16 + l15) * VPAD + quad * 8]);
            accO[ht] = __builtin_amdgcn_mfma_f32_16x16x32_bf16(pf, vf, accO[ht], 0, 0, 0);
        }
    }

    // epilogue: out fp32, C layout col=h, row=t
#pragma unroll
    for (int ht = 0; ht < 4; ++ht)
#pragma unroll
        for (int r = 0; r < 4; ++r) {
            int tg = t0 + wave * 16 + quad * 4 + r;
            out[(b * TB + tg) * HD + ht * 16 + l15] = accO[ht][r] / lrow[r];
        }
}

extern "C" void kernel_launch(void* const* d_in, const int* in_sizes, int n_in,
                              void* d_out, int out_size, void* d_ws, size_t ws_size,
                              hipStream_t stream) {
    const float* x  = (const float*)d_in[0];
    const float* Wk = (const float*)d_in[1];
    const float* Wq = (const float*)d_in[2];
    const float* Wv = (const float*)d_in[3];
    float* out = (float*)d_out;

    short* Wcat = (short*)d_ws;              // 192*1024 bf16
    short* Qb   = Wcat + 192 * 1024;         // 16384*64 each
    short* Kb   = Qb + BT * HD;
    short* Vb   = Kb + BT * HD;

    wconvert<<<192, 256, 0, stream>>>(Wk, Wq, Wv, Wcat);
    qkv_proj<<<BT / 64, 256, 0, stream>>>(x, Wcat, Qb, Kb, Vb);
    flash<<<NB * (TB / 64), 256, 0, stream>>>(Qb, Kb, Vb, out);
}